// Round 10
// baseline (177.175 us; speedup 1.0000x reference)
//
#include <hip/hip_runtime.h>

// Full pipeline decomposition with correct attG sizing (8 MB).
//  bs=64, nq=64, E=256, Hn=8, dh=32, L=4, P=16, BEV=2, Pb=32
//  qb=128 collapses to 64. OFF col (h,f,c)=h*256+2f+c; rp level=f&3;
//  image level=f>>5; attn key=f; output pairs (2q,2q+1) -> rows pj/pj+32.
//
// ws: [0,2M) Qb bf16 4096x256 | [2M,3M) Wtb bf16 2048x256
//     [3M,7M) VTg bf16 [bh][32][128] | [7M,15M) attG bf16 [bh][64][128]
//     [15M,31.78M) OFFb bf16 4096x2048          (total 31.78 MB)

typedef short  s16x8 __attribute__((ext_vector_type(8)));
typedef short  s16x4 __attribute__((ext_vector_type(4)));
typedef float  f32x4 __attribute__((ext_vector_type(4)));

__device__ __forceinline__ unsigned short f2bf(float f) {
    union { float f; unsigned u; } v; v.f = f;
    unsigned r = v.u + 0x7FFFu + ((v.u >> 16) & 1u);   // RNE
    return (unsigned short)(r >> 16);
}
__device__ __forceinline__ float bf2f(unsigned short u) {
    return __uint_as_float(((unsigned)u) << 16);
}
__device__ __forceinline__ s16x8 pack8(const float4 a, const float4 b) {
    s16x8 o;
    o[0] = (short)f2bf(a.x); o[1] = (short)f2bf(a.y);
    o[2] = (short)f2bf(a.z); o[3] = (short)f2bf(a.w);
    o[4] = (short)f2bf(b.x); o[5] = (short)f2bf(b.y);
    o[6] = (short)f2bf(b.z); o[7] = (short)f2bf(b.w);
    return o;
}

// ---------------------------------------------------------------------------
// K1 prep: [0,512) W transpose; [512,1536) query->Qb; [1536,2048) VTg build
// ---------------------------------------------------------------------------
__global__ __launch_bounds__(256) void prep(
    const float* __restrict__ W, const float* __restrict__ query,
    const float* __restrict__ value_hist,
    short* __restrict__ Wtb, short* __restrict__ Qb, short* __restrict__ VTg)
{
    __shared__ float s[32][33];
    const int bx = blockIdx.x, t = threadIdx.x;
    if (bx < 512) {
        const int n0 = (bx & 63) * 32, k0 = (bx >> 6) * 32;
        const int c = t & 31, r0 = t >> 5;
        #pragma unroll
        for (int p = 0; p < 4; ++p) {
            const int r = r0 + p * 8;
            s[r][c] = W[(size_t)(k0 + r) * 2048 + n0 + c];
        }
        __syncthreads();
        #pragma unroll
        for (int p = 0; p < 4; ++p) {
            const int r = r0 + p * 8;
            Wtb[(size_t)(n0 + r) * 256 + k0 + c] = (short)f2bf(s[c][r]);
        }
    } else if (bx < 1536) {
        const int j = bx - 512;                 // 0..1023
        const int i4 = (j * 256 + t) * 4;
        const float4 v = *(const float4*)(query + i4);
        s16x4 o;
        o.x = (short)f2bf(v.x); o.y = (short)f2bf(v.y);
        o.z = (short)f2bf(v.z); o.w = (short)f2bf(v.w);
        *(s16x4*)(Qb + i4) = o;
    } else {
        const int bh = bx - 1536;               // 0..511
        const int b = bh >> 3, h = bh & 7;
        #pragma unroll
        for (int pass = 0; pass < 4; ++pass) {
            const int idx = t + 256 * pass;     // 0..1023
            const int p = idx >> 3;             // 0..127
            const int dg = idx & 7;             // 0..7
            const float* src = (p < 64) ? query : value_hist;
            const float4 v = *(const float4*)(src +
                (size_t)(b * 64 + (p & 63)) * 256 + h * 32 + dg * 4);
            short* o = VTg + ((size_t)bh * 32 + dg * 4) * 128 + p;
            o[0 * 128] = (short)f2bf(v.x);
            o[1 * 128] = (short)f2bf(v.y);
            o[2 * 128] = (short)f2bf(v.z);
            o[3 * 128] = (short)f2bf(v.w);
        }
    }
}

// ---------------------------------------------------------------------------
// K2 gemm: OFFb[4096][2048] = bf16( Qb @ Wtb^T + bias ). 128x128 tile.
// ---------------------------------------------------------------------------
__global__ __launch_bounds__(256) void gemm_k(
    const short* __restrict__ Ab, const short* __restrict__ Wt,
    const float* __restrict__ bias, short* __restrict__ OFFb)
{
    __shared__ __align__(16) short smem[128 * 136];
    short (*Asl)[40] = (short (*)[40])smem;
    short (*Bsl)[40] = (short (*)[40])(smem + 128 * 40);
    short (*Cst)[136] = (short (*)[136])smem;

    const int n0 = blockIdx.x * 128, m0 = blockIdx.y * 128;
    const int t = threadIdx.x, lane = t & 63, wave = t >> 6;
    const int wm0 = (wave >> 1) * 64, wn0 = (wave & 1) * 64;
    const int r = lane & 15, q = lane >> 4;

    f32x4 acc[4][4] = {};
    for (int kc = 0; kc < 256; kc += 32) {
        #pragma unroll
        for (int ss = 0; ss < 2; ++ss) {
            const int seg = t + ss * 256;
            const int row = seg >> 2, off8 = (seg & 3) * 8;
            *(s16x8*)&Asl[row][off8] =
                *(const s16x8*)(Ab + (size_t)(m0 + row) * 256 + kc + off8);
            *(s16x8*)&Bsl[row][off8] =
                *(const s16x8*)(Wt + (size_t)(n0 + row) * 256 + kc + off8);
        }
        __syncthreads();
        s16x8 af[4], bf[4];
        #pragma unroll
        for (int i = 0; i < 4; ++i) {
            af[i] = *(const s16x8*)&Asl[wm0 + i * 16 + r][q * 8];
            bf[i] = *(const s16x8*)&Bsl[wn0 + i * 16 + r][q * 8];
        }
        #pragma unroll
        for (int i = 0; i < 4; ++i)
            #pragma unroll
            for (int j = 0; j < 4; ++j)
                acc[i][j] = __builtin_amdgcn_mfma_f32_16x16x32_bf16(
                    af[i], bf[j], acc[i][j], 0, 0, 0);
        __syncthreads();
    }
    #pragma unroll
    for (int j = 0; j < 4; ++j) {
        const float bb = bias[n0 + wn0 + j * 16 + r];
        #pragma unroll
        for (int i = 0; i < 4; ++i)
            #pragma unroll
            for (int rg = 0; rg < 4; ++rg)
                Cst[wm0 + i * 16 + q * 4 + rg][wn0 + j * 16 + r] =
                    (short)f2bf(acc[i][j][rg] + bb);
    }
    __syncthreads();
    {
        const int row = t >> 1, half = t & 1;
        short* gdst = OFFb + (size_t)(m0 + row) * 2048 + n0 + half * 64;
        const short* lsrc = &Cst[row][half * 64];
        #pragma unroll
        for (int u = 0; u < 8; ++u)
            *(s16x8*)(gdst + u * 8) = *(const s16x8*)(lsrc + u * 8);
    }
}

// ---------------------------------------------------------------------------
// K3 logits: attG[(b*8+h)*64+q][128] = softmax_k(QK^T) bf16. grid (8 h, 64 b);
// wave owns m-tile wave (16 q); frags packed from f32 in-register.
// ---------------------------------------------------------------------------
__global__ __launch_bounds__(256) void logits_k(
    const float* __restrict__ query, const float* __restrict__ key_hist,
    short* __restrict__ attG)
{
    const int h = blockIdx.x, b = blockIdx.y;
    const int t = threadIdx.x, lane = t & 63, wave = t >> 6;
    const int quad = lane >> 4, col = lane & 15;

    const float* qp = query + ((size_t)b * 64 + wave * 16 + col) * 256
                      + h * 32 + quad * 8;
    const s16x8 aq = pack8(*(const float4*)qp, *(const float4*)(qp + 4));
    f32x4 lacc[8];
    #pragma unroll
    for (int t8 = 0; t8 < 8; ++t8) {
        const float* kp = ((t8 < 4)
            ? (query    + ((size_t)b * 64 + 16 * t8 + col) * 256)
            : (key_hist + ((size_t)b * 64 + 16 * (t8 - 4) + col) * 256))
            + h * 32 + quad * 8;
        const s16x8 bk = pack8(*(const float4*)kp, *(const float4*)(kp + 4));
        const f32x4 z = {0.f, 0.f, 0.f, 0.f};
        lacc[t8] = __builtin_amdgcn_mfma_f32_16x16x32_bf16(aq, bk, z, 0, 0, 0);
    }
    #pragma unroll
    for (int r = 0; r < 4; ++r) {
        float m = lacc[0][r];
        #pragma unroll
        for (int t8 = 1; t8 < 8; ++t8) m = fmaxf(m, lacc[t8][r]);
        #pragma unroll
        for (int sh = 1; sh < 16; sh <<= 1) m = fmaxf(m, __shfl_xor(m, sh, 64));
        float e[8], ssum = 0.f;
        #pragma unroll
        for (int t8 = 0; t8 < 8; ++t8) {
            e[t8] = __expf(lacc[t8][r] - m); ssum += e[t8];
        }
        #pragma unroll
        for (int sh = 1; sh < 16; sh <<= 1) ssum += __shfl_xor(ssum, sh, 64);
        const float inv = 1.0f / ssum;
        const int q = wave * 16 + 4 * quad + r;
        short* dst = attG + ((size_t)(b * 8 + h) * 64 + q) * 128;
        #pragma unroll
        for (int t8 = 0; t8 < 8; ++t8)
            dst[16 * t8 + col] = (short)f2bf(e[t8] * inv);
    }
}

// ---------------------------------------------------------------------------
// K4 scatter_av: grid (8 h, 64 b, 2 s); 32 q/block; LDS only Am (17 KB).
// OFF dwords + attn weights fully prefetched into registers (unrolled) ->
// scatter (ds_add) -> Am bf16 -> AV MFMA (VTg) -> pair-mean + residual.
// ---------------------------------------------------------------------------
__global__ __launch_bounds__(256) void scatter_av(
    const float* __restrict__ query, const float* __restrict__ refp,
    const short* __restrict__ VTg, const unsigned* __restrict__ OFFu,
    const short* __restrict__ attG, float* __restrict__ out)
{
    const int h = blockIdx.x, b = blockIdx.y, s = blockIdx.z;
    const int q0 = s * 32;
    const int t = threadIdx.x, lane = t & 63, wave = t >> 6;
    const int quad = lane >> 4, col = lane & 15;

    __shared__ __align__(16) float Am[32 * 132];    // 16896 B
    short* Amb = (short*)Am;                        // alias [32][136] bf16

    // prefetch: 16 OFF dwords + 16 attn weights + 8 refp (all independent)
    const int q = t >> 3, fg = t & 7;
    const int qg = b * 64 + q0 + q;
    unsigned offv[16];
    {
        const unsigned* offrow = OFFu + (size_t)qg * 1024 + h * 128;
        #pragma unroll
        for (int i = 0; i < 16; ++i) offv[i] = offrow[fg + 8 * i];
    }
    float av[16];
    {
        const short* arow = attG + ((size_t)(b * 8 + h) * 64 + q0 + q) * 128;
        #pragma unroll
        for (int i = 0; i < 16; ++i)
            av[i] = bf2f((unsigned short)arow[fg + 8 * i]);
    }
    float rpl[8];
    {
        const float* rp8 = refp + (size_t)qg * 8;
        #pragma unroll
        for (int j = 0; j < 8; ++j) rpl[j] = rp8[j];
    }

    // zero Am
    {
        #pragma unroll
        for (int u = 0; u < 17; ++u) {
            const int idx = t + 256 * u;
            if (idx < 32 * 132) Am[idx] = 0.f;
        }
    }
    __syncthreads();

    // scatter (fully unrolled; f = fg + 8i)
    {
        float* rowW = &Am[q * 132];
        #pragma unroll
        for (int i = 0; i < 16; ++i) {
            const int f = fg + 8 * i;
            const unsigned u = offv[i];
            const float ox = __uint_as_float(u << 16);
            const float oy = __uint_as_float(u & 0xFFFF0000u);
            const float a = av[i];
            const int l = f & 3;
            const float gx = 8.f * (rpl[l * 2 + 0] + ox * 0.125f) - 0.5f;
            const float gy = 4.f * (rpl[l * 2 + 1] + oy * 0.25f) - 0.5f;
            const float x0f = floorf(gx), y0f = floorf(gy);
            const float wx = gx - x0f, wy = gy - y0f;
            const int x0 = (int)x0f, y0 = (int)y0f;
            const int base = (f >> 5) * 32;
            const bool xv0 = (x0 >= 0) && (x0 < 8);
            const bool xv1 = (x0 >= -1) && (x0 < 7);
            const bool yv0 = (y0 >= 0) && (y0 < 4);
            const bool yv1 = (y0 >= -1) && (y0 < 3);
            if (xv0 && yv0) unsafeAtomicAdd(&rowW[base + y0 * 8 + x0],           a * (1.f - wx) * (1.f - wy));
            if (xv1 && yv0) unsafeAtomicAdd(&rowW[base + y0 * 8 + x0 + 1],       a * wx * (1.f - wy));
            if (xv0 && yv1) unsafeAtomicAdd(&rowW[base + (y0 + 1) * 8 + x0],     a * (1.f - wx) * wy);
            if (xv1 && yv1) unsafeAtomicAdd(&rowW[base + (y0 + 1) * 8 + x0 + 1], a * wx * wy);
        }
    }
    __syncthreads();

    // Am -> bf16
    {
        const int cq = t >> 3, cc = (t & 7) * 16;
        float vreg[16];
        #pragma unroll
        for (int u = 0; u < 4; ++u) {
            const float4 v = *(const float4*)&Am[cq * 132 + cc + 4 * u];
            vreg[4 * u + 0] = v.x; vreg[4 * u + 1] = v.y;
            vreg[4 * u + 2] = v.z; vreg[4 * u + 3] = v.w;
        }
        __syncthreads();
        #pragma unroll
        for (int u = 0; u < 2; ++u) {
            s16x8 o;
            #pragma unroll
            for (int j = 0; j < 8; ++j) o[j] = (short)f2bf(vreg[u * 8 + j]);
            *(s16x8*)&Amb[cq * 136 + cc + u * 8] = o;
        }
    }
    __syncthreads();

    // AV: wave -> (m-tile mw = wave&1, n-tile nt = wave>>1); pair-mean + res
    {
        const int mw = wave & 1, nt = wave >> 1;
        f32x4 oacc = {};
        #pragma unroll
        for (int ks = 0; ks < 4; ++ks) {
            const s16x8 af = *(const s16x8*)&Amb[(mw * 16 + col) * 136
                                                 + ks * 32 + quad * 8];
            const s16x8 bv = *(const s16x8*)(VTg +
                ((size_t)(b * 8 + h) * 32 + nt * 16 + col) * 128
                + ks * 32 + quad * 8);
            oacc = __builtin_amdgcn_mfma_f32_16x16x32_bf16(af, bv, oacc, 0, 0, 0);
        }
        const int d = h * 32 + nt * 16 + col;
        #pragma unroll
        for (int pr = 0; pr < 2; ++pr) {
            const float avg = 0.5f * (oacc[2 * pr] + oacc[2 * pr + 1]);
            const int pj = (q0 >> 1) + mw * 8 + quad * 2 + pr;
            const size_t re = ((size_t)b * 64 + pj) * 256 + d;
            const size_t ro = ((size_t)b * 64 + pj + 32) * 256 + d;
            out[re] = query[re] + avg;
            out[ro] = query[ro] + avg;
        }
    }
}

extern "C" void kernel_launch(void* const* d_in, const int* in_sizes, int n_in,
                              void* d_out, int out_size, void* d_ws, size_t ws_size,
                              hipStream_t stream) {
    (void)in_sizes; (void)n_in; (void)out_size; (void)ws_size;
    const float* query      = (const float*)d_in[0];
    const float* key_hist   = (const float*)d_in[1];
    const float* value_hist = (const float*)d_in[2];
    const float* refp       = (const float*)d_in[3];
    const float* W_off      = (const float*)d_in[5];
    const float* b_off      = (const float*)d_in[6];

    char* ws = (char*)d_ws;
    short* Qb   = (short*)(ws);                    // 2 MB
    short* Wtb  = (short*)(ws + (2u  << 20));      // 1 MB
    short* VTg  = (short*)(ws + (3u  << 20));      // 4 MB
    short* attG = (short*)(ws + (7u  << 20));      // 8 MB
    short* OFFb = (short*)(ws + (15u << 20));      // 16.78 MB
    float* out  = (float*)d_out;

    prep<<<2048, 256, 0, stream>>>(W_off, query, value_hist, Wtb, Qb, VTg);
    gemm_k<<<dim3(16, 32), 256, 0, stream>>>(Qb, Wtb, b_off, OFFb);
    logits_k<<<dim3(8, 64), 256, 0, stream>>>(query, key_hist, attG);
    scatter_av<<<dim3(8, 64, 2), 256, 0, stream>>>(query, refp, VTg,
                                                   (const unsigned*)OFFb,
                                                   attG, out);
}